// Round 6
// baseline (8006.962 us; speedup 1.0000x reference)
//
#include <hip/hip_runtime.h>
#include <hip/hip_bf16.h>
#include <cstdint>

// ---------------------------------------------------------------------------
// GemResNetBlock: two gauge-equivariant convs + Fourier ReLU + linear residual
#define NV     20000
#define NE     160000
#define IC1    16
#define OC     32
#define DIN    5      // 2*order+1, order=2 everywhere
#define NSLOT  49     // nonzeros of the 19-basis equivariant kernel
#define TILE   4      // edges per register tile (wk-load amortization)
// ---------------------------------------------------------------------------
// Slot tables GENERATED AT COMPILE TIME by a literal transliteration of the
// reference build_kernel_basis (content verified round 4/5: PASS).
struct SlotTables {
    int n;
    int b[64], f[64], i[64], j[64];
    float v[64];
};

constexpr SlotTables make_slots() {
    SlotTables T{};
    float K[19][5][5][5] = {};   // [basis][freq][row i][col j]
    int nb = 0;
    const int BL = 2;
    auto add = [&](int f, const float (*cb)[2], const float (*sb)[2],
                   int m, int n) {
        if (f > BL) return;
        int r0 = (m == 0) ? 0 : (2 * m - 1), nr = (m == 0) ? 1 : 2;
        int c0 = (n == 0) ? 0 : (2 * n - 1), nc = (n == 0) ? 1 : 2;
        for (int a = 0; a < nr; a++)
            for (int bb = 0; bb < nc; bb++) {
                if (f == 0) {
                    K[nb][0][r0 + a][c0 + bb] = cb[a][bb];
                } else {
                    K[nb][2 * f - 1][r0 + a][c0 + bb] = cb[a][bb];
                    K[nb][2 * f    ][r0 + a][c0 + bb] = sb[a][bb];
                }
            }
        nb++;
    };
    const float ONE[2][2]  = {{1, 0}, {0, 0}};
    const float I2[2][2]   = {{1, 0}, {0, 1}};
    const float E2[2][2]   = {{0, -1}, {1, 0}};
    const float S2[2][2]   = {{1, 0}, {0, -1}};
    const float ES2[2][2]  = {{0, 1}, {1, 0}};     // E@S
    const float NS2[2][2]  = {{-1, 0}, {0, 1}};    // -S
    const float C10[2][2]  = {{1, 0}, {0, 0}};
    const float C01[2][2]  = {{0, 0}, {1, 0}};
    const float CM10[2][2] = {{-1, 0}, {0, 0}};
    const float R10[2][2]  = {{1, 0}, {0, 0}};
    const float R01[2][2]  = {{0, 1}, {0, 0}};
    const float RM10[2][2] = {{-1, 0}, {0, 0}};

    for (int m = 0; m <= 2; m++)
        for (int n = 0; n <= 2; n++) {
            if (m == 0 && n == 0) {
                add(0, ONE, ONE, 0, 0);
            } else if (n == 0) {
                add(m, C10, C01, m, 0);
                add(m, C01, CM10, m, 0);
            } else if (m == 0) {
                add(n, R10, R01, 0, n);
                add(n, R01, RM10, 0, n);
            } else {
                int d = m - n;
                int f = d >= 0 ? d : -d;
                float sg = d >= 0 ? 1.f : -1.f;
                const float sgE[2][2]  = {{0, -sg}, {sg, 0}};
                const float msgI[2][2] = {{-sg, 0}, {0, -sg}};
                add(f, I2, sgE, m, n);
                add(f, E2, msgI, m, n);
                add(m + n, S2, ES2, m, n);
                add(m + n, ES2, NS2, m, n);
            }
        }
    T.n = 0;
    for (int i = 0; i < 5; i++)
        for (int b = 0; b < nb; b++)
            for (int f = 0; f < 5; f++)
                for (int j = 0; j < 5; j++)
                    if (K[b][f][i][j] != 0.0f) {
                        T.b[T.n] = b; T.f[T.n] = f; T.i[T.n] = i;
                        T.j[T.n] = j; T.v[T.n] = K[b][f][i][j];
                        T.n++;
                    }
    return T;
}

constexpr SlotTables SL = make_slots();
static_assert(SL.n == NSLOT, "expect 49 kernel-basis nonzeros");
static_assert(SL.i[8] == 0 && SL.i[9] == 1 && SL.i[20] == 1 && SL.i[21] == 2 &&
              SL.i[32] == 2 && SL.i[33] == 3 && SL.i[40] == 3 && SL.i[41] == 4,
              "slot group boundaries");

// Build packed per-slot weights (fp32): wk[(c*NSLOT+s)*32+o] = float2(
//   v*W[b,ring0,o,c], v*W[b,ring1,o,c]).  W layout: [19][2][32][C].
template<int C>
__global__ __launch_bounds__(256) void build_wk(const float* __restrict__ W,
                                                float2* __restrict__ wk) {
    int t = blockIdx.x * 256 + threadIdx.x;
    if (t >= C * NSLOT * 32) return;
    int o = t & 31;
    int s = (t >> 5) % NSLOT;
    int c = (t >> 5) / NSLOT;
    int b = SL.b[s];
    float v = SL.v[s];
    float w0 = v * W[(size_t)((b * 2 + 0) * 32 + o) * C + c];
    float w1 = v * W[(size_t)((b * 2 + 1) * 32 + o) * C + c];
    wk[(c * NSLOT + s) * 32 + o] = make_float2(w0, w1);
}

// ---------------- CSR build (counts/cursor/order live in d_out scratch) ----
__global__ __launch_bounds__(256) void hist_k(const int* __restrict__ ei,
                                              int* __restrict__ counts) {
    int e = blockIdx.x * 256 + threadIdx.x;
    if (e < NE) atomicAdd(&counts[ei[e]], 1);   // ei[e] = dst
}

__global__ __launch_bounds__(1024) void scan_k(const int* __restrict__ counts,
                                               int* __restrict__ cursor) {
    __shared__ int part[1024];
    int t = threadIdx.x;
    int base = t * 20;                      // 1024*20 = 20480 >= NV
    int local[20];
    int s = 0;
    #pragma unroll
    for (int k = 0; k < 20; k++) {
        int idx = base + k;
        int c = (idx < NV) ? counts[idx] : 0;
        local[k] = c; s += c;
    }
    part[t] = s;
    __syncthreads();
    for (int off = 1; off < 1024; off <<= 1) {   // Hillis-Steele inclusive
        int add = (t >= off) ? part[t - off] : 0;
        __syncthreads();
        part[t] += add;
        __syncthreads();
    }
    int run = (t == 0) ? 0 : part[t - 1];        // exclusive base
    #pragma unroll
    for (int k = 0; k < 20; k++) {
        int idx = base + k;
        if (idx < NV) { cursor[idx] = run; run += local[k]; }
    }
}

__global__ __launch_bounds__(256) void scatter_k(const int* __restrict__ ei,
                                                 int* __restrict__ cursor,
                                                 int* __restrict__ order) {
    int e = blockIdx.x * 256 + threadIdx.x;
    if (e >= NE) return;
    int pos = atomicAdd(&cursor[ei[e]], 1);
    order[pos] = e;
}

// ---------------- Atomic-free gather conv, edge-tiled (T=4) ----------------
// Thread (v,o): process v's in-edges in register tiles of TILE edges.  Per
// tile, per-edge scalars (p, rotation) are staged first; the wk weight
// stream (c,s) is then loaded ONCE per tile and applied to all TILE edges
// (12 VALU per 8B wk load vs 3 in round 5 -> 4x less L2 weight traffic).
// Tail edges are masked by zeroing p (their contribution is exactly 0).
template<int C>
__global__ __launch_bounds__(256) void gather_conv(const float* __restrict__ xin,
                                                   const int*   __restrict__ ei,
                                                   const float* __restrict__ pre,
                                                   const float* __restrict__ conn,
                                                   const float2* __restrict__ wk,
                                                   const int* __restrict__ cursor,
                                                   const int* __restrict__ order,
                                                   float* __restrict__ yout) {
    int t = blockIdx.x * 256 + threadIdx.x;
    if (t >= NV * 32) return;
    int o = t & 31;
    int v = t >> 5;
    int beg = (v == 0) ? 0 : cursor[v - 1];
    int end = cursor[v];
    float acc[5] = {0.f, 0.f, 0.f, 0.f, 0.f};

    for (int k0 = beg; k0 < end; k0 += TILE) {
        // ---- stage per-edge scalars for the tile ----
        int   srcb[TILE];
        float pp[TILE][10];
        float c1[TILE], s1[TILE], c2[TILE], s2[TILE];
        #pragma unroll
        for (int tt = 0; tt < TILE; tt++) {
            int kk = k0 + tt;
            bool valid = (kk < end);
            int e = order[valid ? kk : beg];      // safe address for tail
            srcb[tt] = ei[NE + e];
            float al = conn[e];
            float cc = __cosf(al), ss = __sinf(al);
            c1[tt] = cc; s1[tt] = ss;
            c2[tt] = cc * cc - ss * ss; s2[tt] = 2.f * cc * ss;
            float vm = valid ? 1.f : 0.f;         // mask via p
            #pragma unroll
            for (int q = 0; q < 10; q++)
                pp[tt][q] = vm * pre[(size_t)e * 10 + q];
        }
        // ---- channel loop: wk stream amortized over TILE edges ----
        for (int c = 0; c < C; c++) {
            float xt[TILE][5];
            #pragma unroll
            for (int tt = 0; tt < TILE; tt++) {
                const float* xb = xin + ((size_t)srcb[tt] * C + c) * DIN;
                float x0 = xb[0], x1 = xb[1], x2 = xb[2], x3 = xb[3], x4 = xb[4];
                xt[tt][0] = x0;
                xt[tt][1] = c1[tt] * x1 - s1[tt] * x2;
                xt[tt][2] = s1[tt] * x1 + c1[tt] * x2;
                xt[tt][3] = c2[tt] * x3 - s2[tt] * x4;
                xt[tt][4] = s2[tt] * x3 + c2[tt] * x4;
            }
            const float2* wrow = wk + (size_t)(c * NSLOT) * 32 + o;
            #pragma unroll
            for (int s = 0; s < NSLOT; s++) {
                float2 w = wrow[s * 32];
                #pragma unroll
                for (int tt = 0; tt < TILE; tt++) {
                    float m = fmaf(pp[tt][2 * SL.f[s] + 1], w.y,
                                   pp[tt][2 * SL.f[s]] * w.x);
                    acc[SL.i[s]] = fmaf(m, xt[tt][SL.j[s]], acc[SL.i[s]]);
                }
            }
        }
    }
    float* yb = yout + (size_t)t * 5;
    #pragma unroll
    for (int i = 0; i < 5; i++) yb[i] = acc[i];
}

// Fourier-domain ReLU (7 samples, order 2).
__device__ __forceinline__ void fourier_relu(float d0, float d1, float d2,
                                             float d3, float d4, float* out5) {
    float o0 = 0, o1 = 0, o2 = 0, o3 = 0, o4 = 0;
    #pragma unroll
    for (int k = 0; k < 7; k++) {
        float th = (float)k * (6.28318530717958647692f / 7.0f);
        float ck = __cosf(th), sk = __sinf(th);
        float c2k = ck * ck - sk * sk, s2k = 2.f * ck * sk;
        float sv = d0 + ck * d1 + sk * d2 + c2k * d3 + s2k * d4;
        sv = fmaxf(sv, 0.f);
        o0 += sv; o1 += sv * ck; o2 += sv * sk; o3 += sv * c2k; o4 += sv * s2k;
    }
    const float i7 = 1.0f / 7.0f;
    out5[0] = o0 * i7; out5[1] = o1 * (2.f * i7); out5[2] = o2 * (2.f * i7);
    out5[3] = o3 * (2.f * i7); out5[4] = o4 * (2.f * i7);
}

__global__ __launch_bounds__(256) void relu_mid(float* __restrict__ y,
                                                const float* __restrict__ b1) {
    int t = blockIdx.x * 256 + threadIdx.x;     // v*32 + ch
    if (t >= NV * 32) return;
    int ch = t & 31;
    float* yb = y + (size_t)t * 5;
    float r[5];
    fourier_relu(yb[0] + b1[ch], yb[1], yb[2], yb[3], yb[4], r);
    #pragma unroll
    for (int d = 0; d < 5; d++) yb[d] = r[d];
}

__global__ __launch_bounds__(256) void final_k(const float* __restrict__ y2,
                                               const float* __restrict__ x,
                                               const float* __restrict__ Wl,
                                               const float* __restrict__ bl,
                                               const float* __restrict__ b2,
                                               float* __restrict__ out) {
    int t = blockIdx.x * 256 + threadIdx.x;     // v*32 + o
    if (t >= NV * 32) return;
    int o = t & 31;
    int v = t >> 5;
    float r0 = 0, r1 = 0, r2 = 0, r3 = 0, r4 = 0;
    const float* xb = x + (size_t)v * (IC1 * DIN);
    const float* wl = Wl + o * IC1;
    #pragma unroll
    for (int c = 0; c < IC1; c++) {
        float w = wl[c];
        r0 = fmaf(w, xb[c*5+0], r0); r1 = fmaf(w, xb[c*5+1], r1);
        r2 = fmaf(w, xb[c*5+2], r2); r3 = fmaf(w, xb[c*5+3], r3);
        r4 = fmaf(w, xb[c*5+4], r4);
    }
    float blo = bl[o];
    const float* yb = y2 + (size_t)t * 5;
    float d0 = yb[0] + b2[o] + r0 + blo;   // b2 on d=0 only; b_lin on all d
    float d1 = yb[1] + r1 + blo;
    float d2 = yb[2] + r2 + blo;
    float d3 = yb[3] + r3 + blo;
    float d4 = yb[4] + r4 + blo;
    float r[5];
    fourier_relu(d0, d1, d2, d3, d4, r);
    float* ob = out + (size_t)t * 5;
    #pragma unroll
    for (int d = 0; d < 5; d++) ob[d] = r[d];   // fp32 output
}

extern "C" void kernel_launch(void* const* d_in, const int* in_sizes, int n_in,
                              void* d_out, int out_size, void* d_ws, size_t ws_size,
                              hipStream_t stream) {
    const float* x    = (const float*)d_in[0];
    const int*   ei   = (const int*)  d_in[1];
    const float* pre  = (const float*)d_in[2];
    const float* conn = (const float*)d_in[3];
    const float* W1   = (const float*)d_in[4];
    const float* b1   = (const float*)d_in[5];
    const float* W2   = (const float*)d_in[6];
    const float* b2   = (const float*)d_in[7];
    const float* Wl   = (const float*)d_in[8];
    const float* bl   = (const float*)d_in[9];
    float* out = (float*)d_out;

    // ws layout (proven-safe 26.2 MB total): y1, y2, wk1, wk2
    const size_t Y_BYTES = (size_t)NV * 32 * 5 * sizeof(float);     // 12.8 MB
    char* ws = (char*)d_ws;
    float*  y1  = (float*)(ws);
    float*  y2  = (float*)(ws + Y_BYTES);
    float2* wk1 = (float2*)(ws + 2 * Y_BYTES);
    float2* wk2 = (float2*)(ws + 2 * Y_BYTES + (size_t)IC1 * NSLOT * 32 * sizeof(float2));

    // CSR scratch lives in d_out (dead by the time final_k overwrites it)
    int* counts = (int*)d_out;
    int* cursor = counts + NV;
    int* order  = cursor + NV;

    hipMemsetAsync(counts, 0, NV * sizeof(int), stream);

    build_wk<IC1><<<(IC1 * NSLOT * 32 + 255) / 256, 256, 0, stream>>>(W1, wk1);
    build_wk<OC> <<<(OC  * NSLOT * 32 + 255) / 256, 256, 0, stream>>>(W2, wk2);

    hist_k   <<<(NE + 255) / 256, 256, 0, stream>>>(ei, counts);
    scan_k   <<<1, 1024, 0, stream>>>(counts, cursor);
    scatter_k<<<(NE + 255) / 256, 256, 0, stream>>>(ei, cursor, order);

    gather_conv<IC1><<<(NV * 32 + 255) / 256, 256, 0, stream>>>(
        x,  ei, pre, conn, wk1, cursor, order, y1);
    relu_mid<<<(NV * 32 + 255) / 256, 256, 0, stream>>>(y1, b1);
    gather_conv<OC> <<<(NV * 32 + 255) / 256, 256, 0, stream>>>(
        y1, ei, pre, conn, wk2, cursor, order, y2);
    final_k<<<(NV * 32 + 255) / 256, 256, 0, stream>>>(y2, x, Wl, bl, b2, out);
}

// Round 7
// 7858.498 us; speedup vs baseline: 1.0189x; 1.0189x over previous
//
#include <hip/hip_runtime.h>
#include <hip/hip_bf16.h>
#include <cstdint>

// ---------------------------------------------------------------------------
// GemResNetBlock: two gauge-equivariant convs + Fourier ReLU + linear residual
#define NV     20000
#define NE     160000
#define IC1    16
#define OC     32
#define DIN    5      // 2*order+1, order=2 everywhere
#define NSLOT  49     // nonzeros of the 19-basis equivariant kernel
// ---------------------------------------------------------------------------
// Slot tables GENERATED AT COMPILE TIME by a literal transliteration of the
// reference build_kernel_basis (content verified rounds 4-6: PASS).
struct SlotTables {
    int n;
    int b[64], f[64], i[64], j[64];
    float v[64];
};

constexpr SlotTables make_slots() {
    SlotTables T{};
    float K[19][5][5][5] = {};   // [basis][freq][row i][col j]
    int nb = 0;
    const int BL = 2;
    auto add = [&](int f, const float (*cb)[2], const float (*sb)[2],
                   int m, int n) {
        if (f > BL) return;
        int r0 = (m == 0) ? 0 : (2 * m - 1), nr = (m == 0) ? 1 : 2;
        int c0 = (n == 0) ? 0 : (2 * n - 1), nc = (n == 0) ? 1 : 2;
        for (int a = 0; a < nr; a++)
            for (int bb = 0; bb < nc; bb++) {
                if (f == 0) {
                    K[nb][0][r0 + a][c0 + bb] = cb[a][bb];
                } else {
                    K[nb][2 * f - 1][r0 + a][c0 + bb] = cb[a][bb];
                    K[nb][2 * f    ][r0 + a][c0 + bb] = sb[a][bb];
                }
            }
        nb++;
    };
    const float ONE[2][2]  = {{1, 0}, {0, 0}};
    const float I2[2][2]   = {{1, 0}, {0, 1}};
    const float E2[2][2]   = {{0, -1}, {1, 0}};
    const float S2[2][2]   = {{1, 0}, {0, -1}};
    const float ES2[2][2]  = {{0, 1}, {1, 0}};     // E@S
    const float NS2[2][2]  = {{-1, 0}, {0, 1}};    // -S
    const float C10[2][2]  = {{1, 0}, {0, 0}};
    const float C01[2][2]  = {{0, 0}, {1, 0}};
    const float CM10[2][2] = {{-1, 0}, {0, 0}};
    const float R10[2][2]  = {{1, 0}, {0, 0}};
    const float R01[2][2]  = {{0, 1}, {0, 0}};
    const float RM10[2][2] = {{-1, 0}, {0, 0}};

    for (int m = 0; m <= 2; m++)
        for (int n = 0; n <= 2; n++) {
            if (m == 0 && n == 0) {
                add(0, ONE, ONE, 0, 0);
            } else if (n == 0) {
                add(m, C10, C01, m, 0);
                add(m, C01, CM10, m, 0);
            } else if (m == 0) {
                add(n, R10, R01, 0, n);
                add(n, R01, RM10, 0, n);
            } else {
                int d = m - n;
                int f = d >= 0 ? d : -d;
                float sg = d >= 0 ? 1.f : -1.f;
                const float sgE[2][2]  = {{0, -sg}, {sg, 0}};
                const float msgI[2][2] = {{-sg, 0}, {0, -sg}};
                add(f, I2, sgE, m, n);
                add(f, E2, msgI, m, n);
                add(m + n, S2, ES2, m, n);
                add(m + n, ES2, NS2, m, n);
            }
        }
    T.n = 0;
    for (int i = 0; i < 5; i++)
        for (int b = 0; b < nb; b++)
            for (int f = 0; f < 5; f++)
                for (int j = 0; j < 5; j++)
                    if (K[b][f][i][j] != 0.0f) {
                        T.b[T.n] = b; T.f[T.n] = f; T.i[T.n] = i;
                        T.j[T.n] = j; T.v[T.n] = K[b][f][i][j];
                        T.n++;
                    }
    return T;
}

constexpr SlotTables SL = make_slots();
static_assert(SL.n == NSLOT, "expect 49 kernel-basis nonzeros");
static_assert(SL.i[8] == 0 && SL.i[9] == 1 && SL.i[20] == 1 && SL.i[21] == 2 &&
              SL.i[32] == 2 && SL.i[33] == 3 && SL.i[40] == 3 && SL.i[41] == 4,
              "slot group boundaries");

// Build packed per-slot weights (fp32): wk[(c*NSLOT+s)*32+o] = float2(
//   v*W[b,ring0,o,c], v*W[b,ring1,o,c]).  W layout: [19][2][32][C].
template<int C>
__global__ __launch_bounds__(256) void build_wk(const float* __restrict__ W,
                                                float2* __restrict__ wk) {
    int t = blockIdx.x * 256 + threadIdx.x;
    if (t >= C * NSLOT * 32) return;
    int o = t & 31;
    int s = (t >> 5) % NSLOT;
    int c = (t >> 5) / NSLOT;
    int b = SL.b[s];
    float v = SL.v[s];
    float w0 = v * W[(size_t)((b * 2 + 0) * 32 + o) * C + c];
    float w1 = v * W[(size_t)((b * 2 + 1) * 32 + o) * C + c];
    wk[(c * NSLOT + s) * 32 + o] = make_float2(w0, w1);
}

// ---------------- CSR build (counts/cursor/order live in d_out scratch) ----
__global__ __launch_bounds__(256) void hist_k(const int* __restrict__ ei,
                                              int* __restrict__ counts) {
    int e = blockIdx.x * 256 + threadIdx.x;
    if (e < NE) atomicAdd(&counts[ei[e]], 1);   // ei[e] = dst
}

__global__ __launch_bounds__(1024) void scan_k(const int* __restrict__ counts,
                                               int* __restrict__ cursor) {
    __shared__ int part[1024];
    int t = threadIdx.x;
    int base = t * 20;                      // 1024*20 = 20480 >= NV
    int local[20];
    int s = 0;
    #pragma unroll
    for (int k = 0; k < 20; k++) {
        int idx = base + k;
        int c = (idx < NV) ? counts[idx] : 0;
        local[k] = c; s += c;
    }
    part[t] = s;
    __syncthreads();
    for (int off = 1; off < 1024; off <<= 1) {   // Hillis-Steele inclusive
        int add = (t >= off) ? part[t - off] : 0;
        __syncthreads();
        part[t] += add;
        __syncthreads();
    }
    int run = (t == 0) ? 0 : part[t - 1];        // exclusive base
    #pragma unroll
    for (int k = 0; k < 20; k++) {
        int idx = base + k;
        if (idx < NV) { cursor[idx] = run; run += local[k]; }
    }
}

__global__ __launch_bounds__(256) void scatter_k(const int* __restrict__ ei,
                                                 int* __restrict__ cursor,
                                                 int* __restrict__ order) {
    int e = blockIdx.x * 256 + threadIdx.x;
    if (e >= NE) return;
    int pos = atomicAdd(&cursor[ei[e]], 1);
    order[pos] = e;
}

// ---------------- Atomic-free gather conv, BATCHED LOADS -------------------
// Rounds 4-6 post-mortem: the conv was load-LATENCY-serial (~200 cyc/load,
// zero MLP) because the slot loop was load->use adjacent.  Fix: per channel,
// issue ALL 49 weight loads + the 5 x-row loads into registers (phase 1),
// THEN consume (phase 2).  Latency paid once per 54-load batch, not per load.
template<int C>
__global__ __launch_bounds__(256) void gather_conv(const float* __restrict__ xin,
                                                   const int*   __restrict__ ei,
                                                   const float* __restrict__ pre,
                                                   const float* __restrict__ conn,
                                                   const float2* __restrict__ wk,
                                                   const int* __restrict__ cursor,
                                                   const int* __restrict__ order,
                                                   float* __restrict__ yout) {
    int t = blockIdx.x * 256 + threadIdx.x;
    if (t >= NV * 32) return;
    int o = t & 31;
    int v = t >> 5;
    int beg = (v == 0) ? 0 : cursor[v - 1];
    int end = cursor[v];
    float acc[5] = {0.f, 0.f, 0.f, 0.f, 0.f};
    const float2* wbase = wk + o;

    for (int k = beg; k < end; k++) {
        int e = order[k];
        int src = ei[NE + e];              // edge_index[1] = src
        float al = conn[e];
        float c1 = __cosf(al), s1 = __sinf(al);
        float c2 = c1 * c1 - s1 * s1, s2 = 2.0f * c1 * s1;
        float p[10];
        #pragma unroll
        for (int q = 0; q < 10; q++) p[q] = pre[(size_t)e * 10 + q];
        const float* xb = xin + (size_t)src * (C * DIN);

        for (int c = 0; c < C; c++) {
            // ---- phase 1: issue the whole load batch (independent) ----
            float2 wreg[NSLOT];
            const float2* wrow = wbase + (size_t)c * NSLOT * 32;
            #pragma unroll
            for (int s = 0; s < NSLOT; s++) wreg[s] = wrow[s * 32];
            float x0 = xb[c*5+0], x1 = xb[c*5+1], x2 = xb[c*5+2],
                  x3 = xb[c*5+3], x4 = xb[c*5+4];
            // ---- phase 2: consume ----
            float xt[5];
            xt[0] = x0;
            xt[1] = c1 * x1 - s1 * x2;
            xt[2] = s1 * x1 + c1 * x2;
            xt[3] = c2 * x3 - s2 * x4;
            xt[4] = s2 * x3 + c2 * x4;
            #pragma unroll
            for (int s = 0; s < NSLOT; s++) {
                float2 w = wreg[s];
                float m = fmaf(p[2 * SL.f[s] + 1], w.y, p[2 * SL.f[s]] * w.x);
                acc[SL.i[s]] = fmaf(m, xt[SL.j[s]], acc[SL.i[s]]);
            }
        }
    }
    float* yb = yout + (size_t)t * 5;
    #pragma unroll
    for (int i = 0; i < 5; i++) yb[i] = acc[i];
}

// Fourier-domain ReLU (7 samples, order 2).
__device__ __forceinline__ void fourier_relu(float d0, float d1, float d2,
                                             float d3, float d4, float* out5) {
    float o0 = 0, o1 = 0, o2 = 0, o3 = 0, o4 = 0;
    #pragma unroll
    for (int k = 0; k < 7; k++) {
        float th = (float)k * (6.28318530717958647692f / 7.0f);
        float ck = __cosf(th), sk = __sinf(th);
        float c2k = ck * ck - sk * sk, s2k = 2.f * ck * sk;
        float sv = d0 + ck * d1 + sk * d2 + c2k * d3 + s2k * d4;
        sv = fmaxf(sv, 0.f);
        o0 += sv; o1 += sv * ck; o2 += sv * sk; o3 += sv * c2k; o4 += sv * s2k;
    }
    const float i7 = 1.0f / 7.0f;
    out5[0] = o0 * i7; out5[1] = o1 * (2.f * i7); out5[2] = o2 * (2.f * i7);
    out5[3] = o3 * (2.f * i7); out5[4] = o4 * (2.f * i7);
}

__global__ __launch_bounds__(256) void relu_mid(float* __restrict__ y,
                                                const float* __restrict__ b1) {
    int t = blockIdx.x * 256 + threadIdx.x;     // v*32 + ch
    if (t >= NV * 32) return;
    int ch = t & 31;
    float* yb = y + (size_t)t * 5;
    float r[5];
    fourier_relu(yb[0] + b1[ch], yb[1], yb[2], yb[3], yb[4], r);
    #pragma unroll
    for (int d = 0; d < 5; d++) yb[d] = r[d];
}

__global__ __launch_bounds__(256) void final_k(const float* __restrict__ y2,
                                               const float* __restrict__ x,
                                               const float* __restrict__ Wl,
                                               const float* __restrict__ bl,
                                               const float* __restrict__ b2,
                                               float* __restrict__ out) {
    int t = blockIdx.x * 256 + threadIdx.x;     // v*32 + o
    if (t >= NV * 32) return;
    int o = t & 31;
    int v = t >> 5;
    float r0 = 0, r1 = 0, r2 = 0, r3 = 0, r4 = 0;
    const float* xb = x + (size_t)v * (IC1 * DIN);
    const float* wl = Wl + o * IC1;
    #pragma unroll
    for (int c = 0; c < IC1; c++) {
        float w = wl[c];
        r0 = fmaf(w, xb[c*5+0], r0); r1 = fmaf(w, xb[c*5+1], r1);
        r2 = fmaf(w, xb[c*5+2], r2); r3 = fmaf(w, xb[c*5+3], r3);
        r4 = fmaf(w, xb[c*5+4], r4);
    }
    float blo = bl[o];
    const float* yb = y2 + (size_t)t * 5;
    float d0 = yb[0] + b2[o] + r0 + blo;   // b2 on d=0 only; b_lin on all d
    float d1 = yb[1] + r1 + blo;
    float d2 = yb[2] + r2 + blo;
    float d3 = yb[3] + r3 + blo;
    float d4 = yb[4] + r4 + blo;
    float r[5];
    fourier_relu(d0, d1, d2, d3, d4, r);
    float* ob = out + (size_t)t * 5;
    #pragma unroll
    for (int d = 0; d < 5; d++) ob[d] = r[d];   // fp32 output
}

extern "C" void kernel_launch(void* const* d_in, const int* in_sizes, int n_in,
                              void* d_out, int out_size, void* d_ws, size_t ws_size,
                              hipStream_t stream) {
    const float* x    = (const float*)d_in[0];
    const int*   ei   = (const int*)  d_in[1];
    const float* pre  = (const float*)d_in[2];
    const float* conn = (const float*)d_in[3];
    const float* W1   = (const float*)d_in[4];
    const float* b1   = (const float*)d_in[5];
    const float* W2   = (const float*)d_in[6];
    const float* b2   = (const float*)d_in[7];
    const float* Wl   = (const float*)d_in[8];
    const float* bl   = (const float*)d_in[9];
    float* out = (float*)d_out;

    // ws layout (proven-safe 26.2 MB total): y1, y2, wk1, wk2
    const size_t Y_BYTES = (size_t)NV * 32 * 5 * sizeof(float);     // 12.8 MB
    char* ws = (char*)d_ws;
    float*  y1  = (float*)(ws);
    float*  y2  = (float*)(ws + Y_BYTES);
    float2* wk1 = (float2*)(ws + 2 * Y_BYTES);
    float2* wk2 = (float2*)(ws + 2 * Y_BYTES + (size_t)IC1 * NSLOT * 32 * sizeof(float2));

    // CSR scratch lives in d_out (dead by the time final_k overwrites it)
    int* counts = (int*)d_out;
    int* cursor = counts + NV;
    int* order  = cursor + NV;

    hipMemsetAsync(counts, 0, NV * sizeof(int), stream);

    build_wk<IC1><<<(IC1 * NSLOT * 32 + 255) / 256, 256, 0, stream>>>(W1, wk1);
    build_wk<OC> <<<(OC  * NSLOT * 32 + 255) / 256, 256, 0, stream>>>(W2, wk2);

    hist_k   <<<(NE + 255) / 256, 256, 0, stream>>>(ei, counts);
    scan_k   <<<1, 1024, 0, stream>>>(counts, cursor);
    scatter_k<<<(NE + 255) / 256, 256, 0, stream>>>(ei, cursor, order);

    gather_conv<IC1><<<(NV * 32 + 255) / 256, 256, 0, stream>>>(
        x,  ei, pre, conn, wk1, cursor, order, y1);
    relu_mid<<<(NV * 32 + 255) / 256, 256, 0, stream>>>(y1, b1);
    gather_conv<OC> <<<(NV * 32 + 255) / 256, 256, 0, stream>>>(
        y1, ei, pre, conn, wk2, cursor, order, y2);
    final_k<<<(NV * 32 + 255) / 256, 256, 0, stream>>>(y2, x, Wl, bl, b2, out);
}

// Round 8
// 527.188 us; speedup vs baseline: 15.1880x; 14.9064x over previous
//
#include <hip/hip_runtime.h>
#include <hip/hip_bf16.h>
#include <cstdint>

// ---------------------------------------------------------------------------
// GemResNetBlock: two gauge-equivariant convs + Fourier ReLU + linear residual
//
// Round-8 structure (rounds 4-7 were load-latency bound re-streaming weights
// per edge): aggregate-then-GEMM factorization.
//   Z[v,c,j,q] = sum_{e in in(v)} xt[e,c,j] * p[e,q]      (zbuild, streaming)
//   y[v,(o,i)] = sum_{(c,j,q)} Z[v,(c,j,q)] * M[(c,j,q),(o,i)]   (dense GEMM)
// with M[(c,j,q),(o,i)] = sum_{s: j_s=j, f_s=q/2, i_s=i} v_s * W[b_s, q&1, o, c].
#define NV     20000
#define NE     160000
#define IC1    16
#define OC     32
#define DIN    5
#define NSLOT  49
#define NOUT   160              // (o,i) = 32*5
// ---------------------------------------------------------------------------
// Slot tables GENERATED AT COMPILE TIME by a literal transliteration of the
// reference build_kernel_basis (content verified rounds 4-7: PASS).
struct SlotTables {
    int n;
    int b[64], f[64], i[64], j[64];
    float v[64];
};

constexpr SlotTables make_slots() {
    SlotTables T{};
    float K[19][5][5][5] = {};   // [basis][freq][row i][col j]
    int nb = 0;
    const int BL = 2;
    auto add = [&](int f, const float (*cb)[2], const float (*sb)[2],
                   int m, int n) {
        if (f > BL) return;
        int r0 = (m == 0) ? 0 : (2 * m - 1), nr = (m == 0) ? 1 : 2;
        int c0 = (n == 0) ? 0 : (2 * n - 1), nc = (n == 0) ? 1 : 2;
        for (int a = 0; a < nr; a++)
            for (int bb = 0; bb < nc; bb++) {
                if (f == 0) {
                    K[nb][0][r0 + a][c0 + bb] = cb[a][bb];
                } else {
                    K[nb][2 * f - 1][r0 + a][c0 + bb] = cb[a][bb];
                    K[nb][2 * f    ][r0 + a][c0 + bb] = sb[a][bb];
                }
            }
        nb++;
    };
    const float ONE[2][2]  = {{1, 0}, {0, 0}};
    const float I2[2][2]   = {{1, 0}, {0, 1}};
    const float E2[2][2]   = {{0, -1}, {1, 0}};
    const float S2[2][2]   = {{1, 0}, {0, -1}};
    const float ES2[2][2]  = {{0, 1}, {1, 0}};
    const float NS2[2][2]  = {{-1, 0}, {0, 1}};
    const float C10[2][2]  = {{1, 0}, {0, 0}};
    const float C01[2][2]  = {{0, 0}, {1, 0}};
    const float CM10[2][2] = {{-1, 0}, {0, 0}};
    const float R10[2][2]  = {{1, 0}, {0, 0}};
    const float R01[2][2]  = {{0, 1}, {0, 0}};
    const float RM10[2][2] = {{-1, 0}, {0, 0}};

    for (int m = 0; m <= 2; m++)
        for (int n = 0; n <= 2; n++) {
            if (m == 0 && n == 0) {
                add(0, ONE, ONE, 0, 0);
            } else if (n == 0) {
                add(m, C10, C01, m, 0);
                add(m, C01, CM10, m, 0);
            } else if (m == 0) {
                add(n, R10, R01, 0, n);
                add(n, R01, RM10, 0, n);
            } else {
                int d = m - n;
                int f = d >= 0 ? d : -d;
                float sg = d >= 0 ? 1.f : -1.f;
                const float sgE[2][2]  = {{0, -sg}, {sg, 0}};
                const float msgI[2][2] = {{-sg, 0}, {0, -sg}};
                add(f, I2, sgE, m, n);
                add(f, E2, msgI, m, n);
                add(m + n, S2, ES2, m, n);
                add(m + n, ES2, NS2, m, n);
            }
        }
    T.n = 0;
    for (int i = 0; i < 5; i++)
        for (int b = 0; b < nb; b++)
            for (int f = 0; f < 5; f++)
                for (int j = 0; j < 5; j++)
                    if (K[b][f][i][j] != 0.0f) {
                        T.b[T.n] = b; T.f[T.n] = f; T.i[T.n] = i;
                        T.j[T.n] = j; T.v[T.n] = K[b][f][i][j];
                        T.n++;
                    }
    return T;
}

constexpr SlotTables SL = make_slots();
static_assert(SL.n == NSLOT, "expect 49 kernel-basis nonzeros");

// ---------------- M build: M[k][n], k=(c*50+j*10+q), n=(o*5+i) -------------
template<int C>
__global__ __launch_bounds__(256) void build_M(const float* __restrict__ W,
                                               float* __restrict__ M) {
    int t = blockIdx.x * 256 + threadIdx.x;
    const int K = C * 50;
    if (t >= K * NOUT) return;
    int n = t % NOUT, k = t / NOUT;
    int o = n / 5, i = n % 5;
    int c = k / 50, r50 = k % 50;
    int j = r50 / 10, q = r50 % 10;
    int f = q >> 1, r = q & 1;
    float acc = 0.f;
    #pragma unroll
    for (int s = 0; s < NSLOT; s++) {
        if (SL.j[s] == j && SL.f[s] == f && SL.i[s] == i)
            acc += SL.v[s] * W[(size_t)((SL.b[s] * 2 + r) * 32 + o) * C + c];
    }
    M[(size_t)k * NOUT + n] = acc;
}

// ---------------- CSR build (scratch in ws) --------------------------------
__global__ __launch_bounds__(256) void hist_k(const int* __restrict__ ei,
                                              int* __restrict__ counts) {
    int e = blockIdx.x * 256 + threadIdx.x;
    if (e < NE) atomicAdd(&counts[ei[e]], 1);   // ei[e] = dst
}

__global__ __launch_bounds__(1024) void scan_k(const int* __restrict__ counts,
                                               int* __restrict__ cursor) {
    __shared__ int part[1024];
    int t = threadIdx.x;
    int base = t * 20;
    int local[20];
    int s = 0;
    #pragma unroll
    for (int k = 0; k < 20; k++) {
        int idx = base + k;
        int c = (idx < NV) ? counts[idx] : 0;
        local[k] = c; s += c;
    }
    part[t] = s;
    __syncthreads();
    for (int off = 1; off < 1024; off <<= 1) {
        int add = (t >= off) ? part[t - off] : 0;
        __syncthreads();
        part[t] += add;
        __syncthreads();
    }
    int run = (t == 0) ? 0 : part[t - 1];
    #pragma unroll
    for (int k = 0; k < 20; k++) {
        int idx = base + k;
        if (idx < NV) { cursor[idx] = run; run += local[k]; }
    }
}

__global__ __launch_bounds__(256) void scatter_k(const int* __restrict__ ei,
                                                 int* __restrict__ cursor,
                                                 int* __restrict__ order) {
    int e = blockIdx.x * 256 + threadIdx.x;
    if (e >= NE) return;
    int pos = atomicAdd(&cursor[ei[e]], 1);
    order[pos] = e;
}

// ---------------- Z build: thread (v,c) accumulates Z[v,c,5,10] ------------
template<int C>
__global__ __launch_bounds__(256) void zbuild(const float* __restrict__ xin,
                                              const int*   __restrict__ ei,
                                              const float* __restrict__ pre,
                                              const float* __restrict__ conn,
                                              const int* __restrict__ cursor,
                                              const int* __restrict__ order,
                                              float* __restrict__ Z,
                                              int v0, int v1) {
    int t = blockIdx.x * 256 + threadIdx.x;
    int rows = (v1 - v0) * C;
    if (t >= rows) return;
    int c = t % C;
    int v = v0 + t / C;
    int beg = (v == 0) ? 0 : cursor[v - 1];
    int end = cursor[v];
    float acc[50];
    #pragma unroll
    for (int z = 0; z < 50; z++) acc[z] = 0.f;

    for (int k = beg; k < end; k++) {
        int e = order[k];
        int src = ei[NE + e];
        float al = conn[e];
        float c1 = __cosf(al), s1 = __sinf(al);
        float c2 = c1 * c1 - s1 * s1, s2 = 2.0f * c1 * s1;
        float p[10];
        #pragma unroll
        for (int q = 0; q < 10; q++) p[q] = pre[(size_t)e * 10 + q];
        const float* xb = xin + ((size_t)src * C + c) * DIN;
        float x0 = xb[0], x1 = xb[1], x2 = xb[2], x3 = xb[3], x4 = xb[4];
        float xt[5];
        xt[0] = x0;
        xt[1] = c1 * x1 - s1 * x2;
        xt[2] = s1 * x1 + c1 * x2;
        xt[3] = c2 * x3 - s2 * x4;
        xt[4] = s2 * x3 + c2 * x4;
        #pragma unroll
        for (int j = 0; j < 5; j++)
            #pragma unroll
            for (int q = 0; q < 10; q++)
                acc[j * 10 + q] = fmaf(xt[j], p[q], acc[j * 10 + q]);
    }
    float* zb = Z + (size_t)t * 50;     // row (v-v0)*C + c, 50 consecutive
    #pragma unroll
    for (int z = 0; z < 50; z++) zb[z] = acc[z];
}

// ---------------- GEMM: y[v, n] = sum_k Z[v,k] * M[k,n] --------------------
// BM=64 vertices, BN=80 (2 n-blocks), BK=32, 256 threads, thread tile 4x5.
template<int K>
__global__ __launch_bounds__(256) void gemm(const float* __restrict__ Z,
                                            const float* __restrict__ M,
                                            float* __restrict__ Y,
                                            int v0, int v1) {
    __shared__ float Zs[32][68];        // pad 68: 16B-aligned rows, b128 reads
    __shared__ float Ms[32][80];
    int t = threadIdx.x;
    int tv = t & 15;                    // 16 v-groups * rm 4 = 64
    int tn = t >> 4;                    // 16 n-groups * rn 5 = 80
    int blk = blockIdx.x;
    int n0 = blockIdx.y * 80;
    int rows = v1 - v0;
    float acc[4][5];
    #pragma unroll
    for (int a = 0; a < 4; a++)
        #pragma unroll
        for (int b = 0; b < 5; b++) acc[a][b] = 0.f;

    // staging index split
    int sv = t >> 2;                    // 0..63  vertex row for Z staging
    int sk0 = (t & 3) * 8;              // 8 consecutive k per thread
    int zrow = blk * 64 + sv;
    if (zrow >= rows) zrow = rows - 1;  // clamp (avoid OOB; masked at store)

    for (int kc = 0; kc < K; kc += 32) {
        // stage Z[32k][64v] transposed
        const float* zg = Z + (size_t)zrow * K + kc + sk0;
        float4 za = *(const float4*)zg;
        float4 zbv = *(const float4*)(zg + 4);
        Zs[sk0 + 0][sv] = za.x;  Zs[sk0 + 1][sv] = za.y;
        Zs[sk0 + 2][sv] = za.z;  Zs[sk0 + 3][sv] = za.w;
        Zs[sk0 + 4][sv] = zbv.x; Zs[sk0 + 5][sv] = zbv.y;
        Zs[sk0 + 6][sv] = zbv.z; Zs[sk0 + 7][sv] = zbv.w;
        // stage M[32k][80n]
        #pragma unroll
        for (int ii = 0; ii < 10; ii++) {
            int flat = t + 256 * ii;            // 0..2559
            int kk = flat / 80, nn = flat % 80;
            Ms[kk][nn] = M[(size_t)(kc + kk) * NOUT + n0 + nn];
        }
        __syncthreads();
        #pragma unroll
        for (int kk = 0; kk < 32; kk++) {
            float zr[4], mr[5];
            #pragma unroll
            for (int a = 0; a < 4; a++) zr[a] = Zs[kk][tv * 4 + a];
            #pragma unroll
            for (int b = 0; b < 5; b++) mr[b] = Ms[kk][tn * 5 + b];
            #pragma unroll
            for (int a = 0; a < 4; a++)
                #pragma unroll
                for (int b = 0; b < 5; b++)
                    acc[a][b] = fmaf(zr[a], mr[b], acc[a][b]);
        }
        __syncthreads();
    }
    #pragma unroll
    for (int a = 0; a < 4; a++) {
        int vl = blk * 64 + tv * 4 + a;
        if (vl < rows) {
            float* yb = Y + (size_t)(v0 + vl) * NOUT + n0 + tn * 5;
            #pragma unroll
            for (int b = 0; b < 5; b++) yb[b] = acc[a][b];
        }
    }
}

// ---------------- Fourier ReLU + epilogues ---------------------------------
__device__ __forceinline__ void fourier_relu(float d0, float d1, float d2,
                                             float d3, float d4, float* out5) {
    float o0 = 0, o1 = 0, o2 = 0, o3 = 0, o4 = 0;
    #pragma unroll
    for (int k = 0; k < 7; k++) {
        float th = (float)k * (6.28318530717958647692f / 7.0f);
        float ck = __cosf(th), sk = __sinf(th);
        float c2k = ck * ck - sk * sk, s2k = 2.f * ck * sk;
        float sv = d0 + ck * d1 + sk * d2 + c2k * d3 + s2k * d4;
        sv = fmaxf(sv, 0.f);
        o0 += sv; o1 += sv * ck; o2 += sv * sk; o3 += sv * c2k; o4 += sv * s2k;
    }
    const float i7 = 1.0f / 7.0f;
    out5[0] = o0 * i7; out5[1] = o1 * (2.f * i7); out5[2] = o2 * (2.f * i7);
    out5[3] = o3 * (2.f * i7); out5[4] = o4 * (2.f * i7);
}

__global__ __launch_bounds__(256) void relu_mid(float* __restrict__ y,
                                                const float* __restrict__ b1) {
    int t = blockIdx.x * 256 + threadIdx.x;     // v*32 + ch
    if (t >= NV * 32) return;
    int ch = t & 31;
    float* yb = y + (size_t)t * 5;
    float r[5];
    fourier_relu(yb[0] + b1[ch], yb[1], yb[2], yb[3], yb[4], r);
    #pragma unroll
    for (int d = 0; d < 5; d++) yb[d] = r[d];
}

__global__ __launch_bounds__(256) void final_k(const float* __restrict__ y2,
                                               const float* __restrict__ x,
                                               const float* __restrict__ Wl,
                                               const float* __restrict__ bl,
                                               const float* __restrict__ b2,
                                               float* __restrict__ out) {
    int t = blockIdx.x * 256 + threadIdx.x;     // v*32 + o
    if (t >= NV * 32) return;
    int o = t & 31;
    int v = t >> 5;
    float r0 = 0, r1 = 0, r2 = 0, r3 = 0, r4 = 0;
    const float* xb = x + (size_t)v * (IC1 * DIN);
    const float* wl = Wl + o * IC1;
    #pragma unroll
    for (int c = 0; c < IC1; c++) {
        float w = wl[c];
        r0 = fmaf(w, xb[c*5+0], r0); r1 = fmaf(w, xb[c*5+1], r1);
        r2 = fmaf(w, xb[c*5+2], r2); r3 = fmaf(w, xb[c*5+3], r3);
        r4 = fmaf(w, xb[c*5+4], r4);
    }
    float blo = bl[o];
    const float* yb = y2 + (size_t)t * 5;
    float d0 = yb[0] + b2[o] + r0 + blo;
    float d1 = yb[1] + r1 + blo;
    float d2 = yb[2] + r2 + blo;
    float d3 = yb[3] + r3 + blo;
    float d4 = yb[4] + r4 + blo;
    float r[5];
    fourier_relu(d0, d1, d2, d3, d4, r);
    float* ob = out + (size_t)t * 5;
    #pragma unroll
    for (int d = 0; d < 5; d++) ob[d] = r[d];
}

extern "C" void kernel_launch(void* const* d_in, const int* in_sizes, int n_in,
                              void* d_out, int out_size, void* d_ws, size_t ws_size,
                              hipStream_t stream) {
    const float* x    = (const float*)d_in[0];
    const int*   ei   = (const int*)  d_in[1];
    const float* pre  = (const float*)d_in[2];
    const float* conn = (const float*)d_in[3];
    const float* W1   = (const float*)d_in[4];
    const float* b1   = (const float*)d_in[5];
    const float* W2   = (const float*)d_in[6];
    const float* b2   = (const float*)d_in[7];
    const float* Wl   = (const float*)d_in[8];
    const float* bl   = (const float*)d_in[9];
    float* out = (float*)d_out;

    const int K1 = IC1 * 50;   // 800
    const int K2 = OC  * 50;   // 1600

    // ws fixed layout: y1 | y2 | M1 | M2 | csr(counts,cursor,order) | Ztail
    const size_t Y_BYTES  = (size_t)NV * NOUT * sizeof(float);      // 12.8 MB
    const size_t M1_BYTES = (size_t)K1 * NOUT * sizeof(float);      // 512 KB
    const size_t M2_BYTES = (size_t)K2 * NOUT * sizeof(float);      // 1 MB
    const size_t CSR_BYTES = (size_t)(2 * NV + NE) * sizeof(int);   // 800 KB
    char* ws = (char*)d_ws;
    float* y1 = (float*)(ws);
    float* y2 = (float*)(ws + Y_BYTES);
    float* M1 = (float*)(ws + 2 * Y_BYTES);
    float* M2 = (float*)(ws + 2 * Y_BYTES + M1_BYTES);
    int* counts = (int*)(ws + 2 * Y_BYTES + M1_BYTES + M2_BYTES);
    int* cursor = counts + NV;
    int* order  = cursor + NV;
    size_t fixed = 2 * Y_BYTES + M1_BYTES + M2_BYTES + CSR_BYTES;   // ~28 MB

    // Z buffer: ws tail if it has room, else d_out (dead until final_k)
    size_t tail = (ws_size > fixed) ? (ws_size - fixed) : 0;
    float* zbuf;
    size_t zcap;
    if (tail >= Y_BYTES) { zbuf = (float*)(ws + fixed); zcap = tail; }
    else                 { zbuf = (float*)d_out;        zcap = Y_BYTES; }
    int chunk1 = (int)(zcap / ((size_t)K1 * 4)); if (chunk1 > NV) chunk1 = NV;
    int chunk2 = (int)(zcap / ((size_t)K2 * 4)); if (chunk2 > NV) chunk2 = NV;

    hipMemsetAsync(counts, 0, NV * sizeof(int), stream);

    build_M<IC1><<<(K1 * NOUT + 255) / 256, 256, 0, stream>>>(W1, M1);
    build_M<OC> <<<(K2 * NOUT + 255) / 256, 256, 0, stream>>>(W2, M2);

    hist_k   <<<(NE + 255) / 256, 256, 0, stream>>>(ei, counts);
    scan_k   <<<1, 1024, 0, stream>>>(counts, cursor);
    scatter_k<<<(NE + 255) / 256, 256, 0, stream>>>(ei, cursor, order);

    // layer 1
    for (int v0 = 0; v0 < NV; v0 += chunk1) {
        int v1 = v0 + chunk1; if (v1 > NV) v1 = NV;
        int rows = v1 - v0;
        zbuild<IC1><<<(rows * IC1 + 255) / 256, 256, 0, stream>>>(
            x, ei, pre, conn, cursor, order, zbuf, v0, v1);
        gemm<K1><<<dim3((rows + 63) / 64, 2), 256, 0, stream>>>(
            zbuf, M1, y1, v0, v1);
    }
    relu_mid<<<(NV * 32 + 255) / 256, 256, 0, stream>>>(y1, b1);
    // layer 2
    for (int v0 = 0; v0 < NV; v0 += chunk2) {
        int v1 = v0 + chunk2; if (v1 > NV) v1 = NV;
        int rows = v1 - v0;
        zbuild<OC><<<(rows * OC + 255) / 256, 256, 0, stream>>>(
            y1, ei, pre, conn, cursor, order, zbuf, v0, v1);
        gemm<K2><<<dim3((rows + 63) / 64, 2), 256, 0, stream>>>(
            zbuf, M2, y2, v0, v1);
    }
    final_k<<<(NV * 32 + 255) / 256, 256, 0, stream>>>(y2, x, Wl, bl, b2, out);
}